// Round 1
// baseline (270.536 us; speedup 1.0000x reference)
//
#include <hip/hip_runtime.h>

typedef __bf16 bf16x8 __attribute__((ext_vector_type(8)));
typedef __bf16 bf16x4 __attribute__((ext_vector_type(4)));
typedef float f32x4 __attribute__((ext_vector_type(4)));

#define EPS 1e-5f

// Precompute (re-runs every launch; d_ws is re-poisoned each time):
//   mt[s][c]      = alpha * M[c][s],  M = W_col @ W_row^T    (bf16 [32][32])
//   bwt2[o][m][k] = zero-padded MFMA A-tile for out-tile o   (bf16 [64][16][32])
//     = bw[63-o][k&15][15-m] when (k>>4) != (o&1), else 0
//   (flip + block-diag zero K-half baked in -> no cndmask, no persistent regs)
__global__ __launch_bounds__(256) void hbsl_precompute(
    const float* __restrict__ bw, const float* __restrict__ W_row,
    const float* __restrict__ W_col, const float* __restrict__ alpha_p,
    __bf16* __restrict__ mt, __bf16* __restrict__ bwt2)
{
    const int t = threadIdx.x;
    if (blockIdx.x == 0) {
        const float alpha = alpha_p[0];
        #pragma unroll
        for (int k4 = 0; k4 < 4; ++k4) {
            int flat = t + 256 * k4;
            int s = flat >> 5, c = flat & 31;
            float acc = 0.f;
            #pragma unroll 8
            for (int kk = 0; kk < 32; ++kk)
                acc += W_col[c * 32 + kk] * W_row[s * 32 + kk];
            mt[s * 32 + c] = (__bf16)(alpha * acc);
        }
    } else {
        const int o = blockIdx.x - 1;      // out-tile 0..63
        const int g = 63 - o;              // source block-diag group
        #pragma unroll
        for (int hh = 0; hh < 2; ++hh) {
            const int idx = t + hh * 256;  // m*32 + k
            const int m = idx >> 5, k = idx & 31;
            float v = 0.f;
            if ((k >> 4) != (o & 1))
                v = bw[g * 256 + (k & 15) * 16 + (15 - m)];
            bwt2[o * 512 + idx] = (__bf16)v;
        }
    }
}

// 512 threads = 8 waves; one block = 16 data rows.
// LN: one wave per row (2 rows/wave, 16 floats/lane) -> single x read, low VGPR.
// xn LDS: [16][1024] bf16 XOR-swizzled (idx ^= (row&7)<<3) -> exactly 32 KB,
//   2-way (free) bank pattern on both the b64 writes and b128 reads.
// MFMA: wave wv owns out tiles [8wv, 8wv+8); bias rides the MFMA C operand.
// Target: 64 VGPR -> 4 blocks x 8 waves = 32 waves/CU.
__global__ __launch_bounds__(512, 8) void hbsl_main(
    const float* __restrict__ x, const float* __restrict__ gamma,
    const float* __restrict__ beta, const float* __restrict__ bias,
    const __bf16* __restrict__ mt, const __bf16* __restrict__ bwt2,
    float* __restrict__ out)
{
    __shared__ __bf16 xn[16 * 1024];
    const int t = threadIdx.x;
    const int lane = t & 63;
    const int wv = t >> 6;                  // 0..7
    const int q = lane >> 4, n = lane & 15; // MFMA lane decomposition
    const int rbase = blockIdx.x * 16;

    // ---- LayerNorm: one wave per row, 2 rows per wave ----
    #pragma unroll
    for (int it = 0; it < 2; ++it) {
        const int r = it * 8 + wv;
        const float* xr = x + (size_t)(rbase + r) * 1024 + lane * 4;
        float4 v0 = *(const float4*)(xr);
        float4 v1 = *(const float4*)(xr + 256);
        float4 v2 = *(const float4*)(xr + 512);
        float4 v3 = *(const float4*)(xr + 768);
        float s  = (v0.x + v0.y + v0.z + v0.w) + (v1.x + v1.y + v1.z + v1.w)
                 + (v2.x + v2.y + v2.z + v2.w) + (v3.x + v3.y + v3.z + v3.w);
        float ss = (v0.x*v0.x + v0.y*v0.y + v0.z*v0.z + v0.w*v0.w)
                 + (v1.x*v1.x + v1.y*v1.y + v1.z*v1.z + v1.w*v1.w)
                 + (v2.x*v2.x + v2.y*v2.y + v2.z*v2.z + v2.w*v2.w)
                 + (v3.x*v3.x + v3.y*v3.y + v3.z*v3.z + v3.w*v3.w);
        #pragma unroll
        for (int msk = 1; msk < 64; msk <<= 1) {
            s  += __shfl_xor(s,  msk, 64);
            ss += __shfl_xor(ss, msk, 64);
        }
        const float mu   = s * (1.f / 1024.f);
        const float rstd = rsqrtf(ss * (1.f / 1024.f) - mu * mu + EPS);
        const int base = r * 1024;
        const int swz  = (r & 7) << 3;
        #pragma unroll
        for (int j = 0; j < 4; ++j) {
            const float4 v = (j == 0) ? v0 : (j == 1) ? v1 : (j == 2) ? v2 : v3;
            const int col = lane * 4 + j * 256;
            const float4 g4 = *(const float4*)(gamma + col);
            const float4 b4 = *(const float4*)(beta + col);
            bf16x4 w;
            w[0] = (__bf16)((v.x - mu) * rstd * g4.x + b4.x);
            w[1] = (__bf16)((v.y - mu) * rstd * g4.y + b4.y);
            w[2] = (__bf16)((v.z - mu) * rstd * g4.z + b4.z);
            w[3] = (__bf16)((v.w - mu) * rstd * g4.w + b4.w);
            *(bf16x4*)(&xn[base + (col ^ swz)]) = w;
        }
    }

    // Monarch A fragments (reused all 4 iterations) — latency hides under barrier.
    const bf16x8 mfrag0 = *(const bf16x8*)(mt + n * 32 + q * 8);
    const bf16x8 mfrag1 = *(const bf16x8*)(mt + (16 + n) * 32 + q * 8);

    __syncthreads();

    // ---- MFMA + store: D col(lane&15)=data row, regs = 4 consecutive out cols ----
    const int rswz = (n & 7) << 3;
    float* orow = out + (size_t)(rbase + n) * 1024;
    #pragma unroll
    for (int p = 0; p < 4; ++p) {
        const int o0 = wv * 8 + 2 * p;     // even out-tile; o1 = o0+1
        const int r  = o0 >> 1;            // monarch window: xn cols [32r, 32r+32)
        const int gp = 31 - r;             // block-diag window: xn cols [32gp, 32gp+32)
        bf16x8 az = *(const bf16x8*)(&xn[n * 1024 + ((r  * 32 + q * 8) ^ rswz)]);
        bf16x8 ay = *(const bf16x8*)(&xn[n * 1024 + ((gp * 32 + q * 8) ^ rswz)]);
        bf16x8 a0 = *(const bf16x8*)(bwt2 + (o0    ) * 512 + n * 32 + q * 8);
        bf16x8 a1 = *(const bf16x8*)(bwt2 + (o0 + 1) * 512 + n * 32 + q * 8);
        f32x4 b0 = *(const f32x4*)(bias + o0 * 16 + q * 4);
        f32x4 b1 = *(const f32x4*)(bias + o0 * 16 + 16 + q * 4);
        f32x4 r0 = __builtin_amdgcn_mfma_f32_16x16x32_bf16(mfrag0, az, b0, 0, 0, 0);
        f32x4 r1 = __builtin_amdgcn_mfma_f32_16x16x32_bf16(mfrag1, az, b1, 0, 0, 0);
        r0 = __builtin_amdgcn_mfma_f32_16x16x32_bf16(a0, ay, r0, 0, 0, 0);
        r1 = __builtin_amdgcn_mfma_f32_16x16x32_bf16(a1, ay, r1, 0, 0, 0);
        float* op = orow + o0 * 16 + q * 4;
        __builtin_nontemporal_store(r0, (f32x4*)op);        // out never re-read:
        __builtin_nontemporal_store(r1, (f32x4*)(op + 16)); // keep x in L3
    }
}

extern "C" void kernel_launch(void* const* d_in, const int* in_sizes, int n_in,
                              void* d_out, int out_size, void* d_ws, size_t ws_size,
                              hipStream_t stream) {
    const float* x      = (const float*)d_in[0];
    const float* gamma  = (const float*)d_in[1];
    const float* beta   = (const float*)d_in[2];
    const float* bw     = (const float*)d_in[3];
    const float* W_row  = (const float*)d_in[4];
    const float* W_col  = (const float*)d_in[5];
    const float* alpha  = (const float*)d_in[6];
    const float* bias   = (const float*)d_in[7];
    float* o = (float*)d_out;

    __bf16* mt   = (__bf16*)d_ws;                    // 32*32*2   = 2048 B
    __bf16* bwt2 = (__bf16*)((char*)d_ws + 2048);    // 64*512*2  = 65536 B

    const int N = in_sizes[0] / 1024;                // 32768 rows

    hipLaunchKernelGGL(hbsl_precompute, dim3(65), dim3(256), 0, stream,
                       bw, W_row, W_col, alpha, mt, bwt2);
    hipLaunchKernelGGL(hbsl_main, dim3(N / 16), dim3(512), 0, stream,
                       x, gamma, beta, bias, mt, bwt2, o);
}